// Round 13
// baseline (656.714 us; speedup 1.0000x reference)
//
#include <hip/hip_runtime.h>
#include <cmath>

#define D  128   // D_EDGE
#define DR 64    // D_RBF
#define NB 32    // nodes per block in stage1

typedef float fx4    __attribute__((ext_vector_type(4)));
typedef float f32x16 __attribute__((ext_vector_type(16)));
typedef short short8v __attribute__((ext_vector_type(8)));

__device__ __forceinline__ float ssp_f(float x) {
  // softplus(x) - log(2), numerically stable
  float m = fmaxf(x, 0.0f);
  float t = __expf(-fabsf(x));
  return m + __logf(1.0f + t) - 0.69314718055994531f;
}

__device__ __forceinline__ short f2bf(float f) {   // fp32 -> bf16 (RNE)
  unsigned u = __float_as_uint(f);
  u = (u + 0x7FFFu + ((u >> 16) & 1u)) >> 16;
  return (short)u;
}

// ---------------------------------------------------------------------------
// stage0: W_eff = W_cat[:, :128] @ W_rbf (128x64), b_eff; also bf16 copy.
// ---------------------------------------------------------------------------
__global__ __launch_bounds__(256) void stage0_kernel(
    const float* __restrict__ W_rbf, const float* __restrict__ b_rbf,
    const float* __restrict__ W_cat, const float* __restrict__ b_cat,
    float* __restrict__ weff, unsigned short* __restrict__ weffh,
    float* __restrict__ beff, int write_bf16)
{
  int gid = blockIdx.x * 256 + threadIdx.x;
  if (gid < D * DR) {
    int o = gid >> 6;
    int r = gid & 63;
    float acc = 0.0f;
    #pragma unroll 8
    for (int d = 0; d < D; ++d)
      acc = fmaf(W_cat[o * 384 + d], W_rbf[d * DR + r], acc);
    weff[gid] = acc;
    if (write_bf16) weffh[gid] = (unsigned short)f2bf(acc);
  }
  if (gid < D) {
    float acc = b_cat[gid];
    #pragma unroll 8
    for (int d = 0; d < D; ++d)
      acc = fmaf(b_rbf[d], W_cat[gid * 384 + d], acc);
    beff[gid] = acc;
  }
}

// ---------------------------------------------------------------------------
// stage1: Pj[n][o] = vi[n] . W_cat[o][128:256], Pi[n][o] = vi[n] . W_cat[o][256:384]
// ---------------------------------------------------------------------------
__global__ __launch_bounds__(256) void stage1_kernel(
    const float* __restrict__ vi, const float* __restrict__ W_cat,
    float* __restrict__ Pj, float* __restrict__ Pi, int N)
{
  __shared__ float vrow[NB * D];
  int base = blockIdx.x * NB;
  int t = threadIdx.x;
  for (int idx = t * 4; idx < NB * D; idx += 1024) {
    int n = base + (idx >> 7);
    float4 v = make_float4(0.f, 0.f, 0.f, 0.f);
    if (n < N) v = *(const float4*)&vi[(long)n * D + (idx & 127)];
    *(float4*)&vrow[idx] = v;
  }
  __syncthreads();

  int o     = t & 127;
  int which = t >> 7;
  const float* w = W_cat + (long)o * 384 + 128 + which * 128;
  float* P = which ? Pi : Pj;

  float acc[NB];
  #pragma unroll
  for (int n = 0; n < NB; ++n) acc[n] = 0.0f;

  for (int dd = 0; dd < D; dd += 4) {
    float4 wv = *(const float4*)&w[dd];
    #pragma unroll
    for (int n = 0; n < NB; ++n) {
      float4 v = *(const float4*)&vrow[n * D + dd];
      acc[n] = fmaf(wv.x, v.x, acc[n]);
      acc[n] = fmaf(wv.y, v.y, acc[n]);
      acc[n] = fmaf(wv.z, v.z, acc[n]);
      acc[n] = fmaf(wv.w, v.w, acc[n]);
    }
  }
  #pragma unroll
  for (int n = 0; n < NB; ++n) {
    int nn = base + n;
    if (nn < N) P[(long)nn * D + o] = acc[n];
  }
}

// ---------------------------------------------------------------------------
// MFMA edge kernel v3. Wave = one 32-edge tile; no LDS/barriers/shfl.
// C/D layout (HW-verified): col=lane&31 (chan), row=(reg&3)+8*(reg>>2)+4*half.
// Register-budgeted for <=128 VGPR (occupancy 4 waves/SIMD; R12's 136 VGPR
// halved occupancy): packed j|i indices (16 regs, N<2^16 guaranteed by host
// guard), per-ct B rotation (32), depth-2 gather rotation (32), A (16),
// acc (16). ct*128 folds into the load's 13-bit imm offset; row*4 folded
// into the Pj/Pi base pointers.
// ---------------------------------------------------------------------------
__global__ __launch_bounds__(256, 4) void edge_mfma_kernel(
    const float* __restrict__ rbf, const int* __restrict__ eidx,
    const unsigned short* __restrict__ weffh, const float* __restrict__ beff,
    const float* __restrict__ Pj, const float* __restrict__ Pi,
    float* __restrict__ out, int E)
{
  const int t    = threadIdx.x;
  const int lane = t & 63;
  const int row  = lane & 31;   // chan within tile / A row
  const int half = lane >> 5;   // k-half selector
  const long wid = (long)blockIdx.x * 4 + (t >> 6);
  const long tb  = wid * 32;
  if (tb >= (long)E) return;

  const char* PjB = (const char*)Pj + row * 4;   // chan offset folded in
  const char* PiB = (const char*)Pi + row * 4;

  // ---- packed per-lane indices for the 16 C/D edge rows (hi16=j, lo16=i) --
  int pk[16];
  #pragma unroll
  for (int reg = 0; reg < 16; ++reg) {
    const int erl = (reg & 3) + 8 * (reg >> 2) + 4 * half;
    long eg = tb + erl; if (eg > (long)E - 1) eg = (long)E - 1;
    const int j = eidx[(long)E + eg];   // edge_index[1] -> h_j -> Pj
    const int i = eidx[eg];             // edge_index[0] -> h_i -> Pi
    pk[reg] = (j << 16) | i;
  }

  // ---- A fragments (fp32 -> bf16), NT loads (rbf is read-once) ----
  long er = tb + row; if (er > (long)E - 1) er = (long)E - 1;
  const float* arow = rbf + er * DR + half * 8;
  short8v A[4];
  #pragma unroll
  for (int ks = 0; ks < 4; ++ks) {
    fx4 lo = __builtin_nontemporal_load((const fx4*)&arow[ks * 16]);
    fx4 hi = __builtin_nontemporal_load((const fx4*)&arow[ks * 16 + 4]);
    short8v a;
    a[0] = f2bf(lo.x); a[1] = f2bf(lo.y); a[2] = f2bf(lo.z); a[3] = f2bf(lo.w);
    a[4] = f2bf(hi.x); a[5] = f2bf(hi.y); a[6] = f2bf(hi.z); a[7] = f2bf(hi.w);
    A[ks] = a;
  }

#define LOAD_B(Bv, biasv, ct)                                                  \
  { _Pragma("unroll")                                                          \
    for (int ks = 0; ks < 4; ++ks)                                             \
      Bv[ks] = *(const short8v*)&weffh[((ct) * 32 + row) * DR + ks * 16 + half * 8]; \
    biasv = beff[(ct) * 32 + row]; }

#define ISSUE_G(gjv, giv, ct)                                                  \
  { _Pragma("unroll")                                                          \
    for (int reg = 0; reg < 16; ++reg) {                                       \
      const int jo = (int)(((unsigned)pk[reg] >> 16) << 9);                    \
      const int io = (int)(((unsigned)pk[reg] & 0xFFFFu) << 9);                \
      gjv[reg] = *(const float*)(PjB + (long)jo + (ct) * 128);                 \
      giv[reg] = *(const float*)(PiB + (long)io + (ct) * 128);                 \
    } }

#define MFMA4(accv, Bv, biasv)                                                 \
  { _Pragma("unroll")                                                          \
    for (int i = 0; i < 16; ++i) accv[i] = biasv;                              \
    accv = __builtin_amdgcn_mfma_f32_32x32x16_bf16(A[0], Bv[0], accv, 0, 0, 0);\
    accv = __builtin_amdgcn_mfma_f32_32x32x16_bf16(A[1], Bv[1], accv, 0, 0, 0);\
    accv = __builtin_amdgcn_mfma_f32_32x32x16_bf16(A[2], Bv[2], accv, 0, 0, 0);\
    accv = __builtin_amdgcn_mfma_f32_32x32x16_bf16(A[3], Bv[3], accv, 0, 0, 0); }

#define EPILOG(gjv, giv, accv, ct)                                             \
  { _Pragma("unroll")                                                          \
    for (int reg = 0; reg < 16; ++reg) {                                       \
      const int erl = (reg & 3) + 8 * (reg >> 2) + 4 * half;                   \
      const long ge = tb + erl;                                                \
      const float v = ssp_f(accv[reg] + gjv[reg] + giv[reg]);                  \
      if (ge < (long)E)                                                        \
        __builtin_nontemporal_store(v, &out[ge * D + (ct) * 32 + row]);        \
    } }

  float gjA[16], giA[16], gjB[16], giB[16];
  short8v BA[4], BB[4];
  float biasA, biasB;
  f32x16 acc;

  // prologue: ct0 weights + gathers in flight
  LOAD_B(BA, biasA, 0);
  ISSUE_G(gjA, giA, 0);

  // ct0: issue ct1, compute ct0
  LOAD_B(BB, biasB, 1);
  ISSUE_G(gjB, giB, 1);
  __builtin_amdgcn_sched_barrier(0);
  MFMA4(acc, BA, biasA);
  EPILOG(gjA, giA, acc, 0);

  // ct1: issue ct2, compute ct1
  LOAD_B(BA, biasA, 2);
  ISSUE_G(gjA, giA, 2);
  __builtin_amdgcn_sched_barrier(0);
  MFMA4(acc, BB, biasB);
  EPILOG(gjB, giB, acc, 1);

  // ct2: issue ct3, compute ct2
  LOAD_B(BB, biasB, 3);
  ISSUE_G(gjB, giB, 3);
  __builtin_amdgcn_sched_barrier(0);
  MFMA4(acc, BA, biasA);
  EPILOG(gjA, giA, acc, 2);

  // ct3: compute
  MFMA4(acc, BB, biasB);
  EPILOG(gjB, giB, acc, 3);

#undef LOAD_B
#undef ISSUE_G
#undef MFMA4
#undef EPILOG
}

// ---------------------------------------------------------------------------
// Fallback (ws too small or N >= 2^16): 3 additive passes over out.
// ---------------------------------------------------------------------------
template<int K, int WS, int WOFF, bool GATHER, bool INIT, bool FINAL>
__global__ __launch_bounds__(256) void pass_kernel(
    const float* __restrict__ src, const int* __restrict__ gidx,
    const float* __restrict__ W, const float* __restrict__ beff,
    float* __restrict__ out, int E)
{
  int e = blockIdx.x * 256 + threadIdx.x;
  if (e >= E) return;
  long rowi = GATHER ? (long)gidx[e] : (long)e;

  float4 rv[K / 4];
  const float4* sp = (const float4*)(src + rowi * K);
  #pragma unroll
  for (int c = 0; c < K / 4; ++c) rv[c] = sp[c];

  float* orow = out + (long)e * D;
  for (int ob = 0; ob < D; ob += 4) {
    float acc[4];
    if (INIT) {
      float4 b4 = *(const float4*)&beff[ob];
      acc[0] = b4.x; acc[1] = b4.y; acc[2] = b4.z; acc[3] = b4.w;
    } else {
      float4 p4 = *(const float4*)&orow[ob];
      acc[0] = p4.x; acc[1] = p4.y; acc[2] = p4.z; acc[3] = p4.w;
    }
    #pragma unroll
    for (int k = 0; k < 4; ++k) {
      const float4* wv = (const float4*)&W[(long)(ob + k) * WS + WOFF];
      float a = acc[k];
      #pragma unroll
      for (int c = 0; c < K / 4; ++c) {
        float4 w4 = wv[c]; float4 r4 = rv[c];
        a = fmaf(w4.x, r4.x, a); a = fmaf(w4.y, r4.y, a);
        a = fmaf(w4.z, r4.z, a); a = fmaf(w4.w, r4.w, a);
      }
      acc[k] = a;
    }
    float4 o4;
    o4.x = FINAL ? ssp_f(acc[0]) : acc[0];
    o4.y = FINAL ? ssp_f(acc[1]) : acc[1];
    o4.z = FINAL ? ssp_f(acc[2]) : acc[2];
    o4.w = FINAL ? ssp_f(acc[3]) : acc[3];
    *(float4*)&orow[ob] = o4;
  }
}

// ---------------------------------------------------------------------------
extern "C" void kernel_launch(void* const* d_in, const int* in_sizes, int n_in,
                              void* d_out, int out_size, void* d_ws, size_t ws_size,
                              hipStream_t stream)
{
  const float* vi    = (const float*)d_in[0];
  const float* rbf   = (const float*)d_in[1];
  const float* W_rbf = (const float*)d_in[2];
  const float* b_rbf = (const float*)d_in[3];
  const float* W_cat = (const float*)d_in[4];
  const float* b_cat = (const float*)d_in[5];
  const int*   eidx  = (const int*)d_in[6];

  const int N = in_sizes[0] / D;
  const int E = in_sizes[6] / 2;
  float* out = (float*)d_out;

  float* ws   = (float*)d_ws;
  float* weff = ws;                               // 8192 floats
  float* beff = ws + D * DR;                      // 128 floats (ends 8320)
  unsigned short* weffh = (unsigned short*)(ws + 8448);  // 8192 ushort
  float* Pj   = ws + 8448 + 4096;                 // N*128 floats
  float* Pi   = Pj + (size_t)N * D;
  size_t need = (8448 + 4096 + 2 * (size_t)N * D) * sizeof(float);

  const int use_fast = (ws_size >= need && E >= 1 && N < 65536);
  stage0_kernel<<<32, 256, 0, stream>>>(W_rbf, b_rbf, W_cat, b_cat,
                                        weff, weffh, beff, use_fast);

  if (use_fast) {
    stage1_kernel<<<(N + NB - 1) / NB, 256, 0, stream>>>(vi, W_cat, Pj, Pi, N);
    long waves = ((long)E + 31) / 32;
    int fblocks = (int)((waves + 3) / 4);
    edge_mfma_kernel<<<fblocks, 256, 0, stream>>>(rbf, eidx, weffh, beff,
                                                  Pj, Pi, out, E);
  } else {
    int eblocks = (E + 255) / 256;
    pass_kernel<DR, DR, 0,  false, true,  false><<<eblocks, 256, 0, stream>>>(rbf, nullptr,  weff,  beff, out, E);
    pass_kernel<D, 384, 128, true, false, false><<<eblocks, 256, 0, stream>>>(vi,  eidx + E, W_cat, beff, out, E);
    pass_kernel<D, 384, 256, true, false, true ><<<eblocks, 256, 0, stream>>>(vi,  eidx,     W_cat, beff, out, E);
  }
}

// Round 14
// 324.043 us; speedup vs baseline: 2.0266x; 2.0266x over previous
//
#include <hip/hip_runtime.h>
#include <cmath>

#define D  128   // D_EDGE
#define DR 64    // D_RBF
#define NB 32    // nodes per block in stage1

typedef float fx4    __attribute__((ext_vector_type(4)));
typedef float f32x16 __attribute__((ext_vector_type(16)));
typedef short short8v __attribute__((ext_vector_type(8)));

__device__ __forceinline__ float ssp_f(float x) {
  // softplus(x) - log(2), numerically stable
  float m = fmaxf(x, 0.0f);
  float t = __expf(-fabsf(x));
  return m + __logf(1.0f + t) - 0.69314718055994531f;
}

__device__ __forceinline__ short f2bf(float f) {   // fp32 -> bf16 (RNE)
  unsigned u = __float_as_uint(f);
  u = (u + 0x7FFFu + ((u >> 16) & 1u)) >> 16;
  return (short)u;
}

// ---------------------------------------------------------------------------
// stage0: W_eff = W_cat[:, :128] @ W_rbf (128x64), b_eff; also bf16 copy.
// ---------------------------------------------------------------------------
__global__ __launch_bounds__(256) void stage0_kernel(
    const float* __restrict__ W_rbf, const float* __restrict__ b_rbf,
    const float* __restrict__ W_cat, const float* __restrict__ b_cat,
    float* __restrict__ weff, unsigned short* __restrict__ weffh,
    float* __restrict__ beff, int write_bf16)
{
  int gid = blockIdx.x * 256 + threadIdx.x;
  if (gid < D * DR) {
    int o = gid >> 6;
    int r = gid & 63;
    float acc = 0.0f;
    #pragma unroll 8
    for (int d = 0; d < D; ++d)
      acc = fmaf(W_cat[o * 384 + d], W_rbf[d * DR + r], acc);
    weff[gid] = acc;
    if (write_bf16) weffh[gid] = (unsigned short)f2bf(acc);
  }
  if (gid < D) {
    float acc = b_cat[gid];
    #pragma unroll 8
    for (int d = 0; d < D; ++d)
      acc = fmaf(b_rbf[d], W_cat[gid * 384 + d], acc);
    beff[gid] = acc;
  }
}

// ---------------------------------------------------------------------------
// stage1: Pj[n][o] = vi[n] . W_cat[o][128:256], Pi[n][o] = vi[n] . W_cat[o][256:384]
// ---------------------------------------------------------------------------
__global__ __launch_bounds__(256) void stage1_kernel(
    const float* __restrict__ vi, const float* __restrict__ W_cat,
    float* __restrict__ Pj, float* __restrict__ Pi, int N)
{
  __shared__ float vrow[NB * D];
  int base = blockIdx.x * NB;
  int t = threadIdx.x;
  for (int idx = t * 4; idx < NB * D; idx += 1024) {
    int n = base + (idx >> 7);
    float4 v = make_float4(0.f, 0.f, 0.f, 0.f);
    if (n < N) v = *(const float4*)&vi[(long)n * D + (idx & 127)];
    *(float4*)&vrow[idx] = v;
  }
  __syncthreads();

  int o     = t & 127;
  int which = t >> 7;
  const float* w = W_cat + (long)o * 384 + 128 + which * 128;
  float* P = which ? Pi : Pj;

  float acc[NB];
  #pragma unroll
  for (int n = 0; n < NB; ++n) acc[n] = 0.0f;

  for (int dd = 0; dd < D; dd += 4) {
    float4 wv = *(const float4*)&w[dd];
    #pragma unroll
    for (int n = 0; n < NB; ++n) {
      float4 v = *(const float4*)&vrow[n * D + dd];
      acc[n] = fmaf(wv.x, v.x, acc[n]);
      acc[n] = fmaf(wv.y, v.y, acc[n]);
      acc[n] = fmaf(wv.z, v.z, acc[n]);
      acc[n] = fmaf(wv.w, v.w, acc[n]);
    }
  }
  #pragma unroll
  for (int n = 0; n < NB; ++n) {
    int nn = base + n;
    if (nn < N) P[(long)nn * D + o] = acc[n];
  }
}

// ---------------------------------------------------------------------------
// MFMA edge kernel v4 = R12 pipeline with packed indices, NO min-waves bound
// (R13: forcing waves/EU made the allocator spill 900MB to scratch; R3 same).
// Wave = one 32-edge tile; no LDS/barriers/shfl.
// C/D layout (HW-verified): col=lane&31 (chan), row=(reg&3)+8*(reg>>2)+4*half.
// Register budget (target <=128, the occupancy boundary): pk 16 + A 16 +
// acc 16 + B 2x16=32 + G 2x16=32 + addr/temps ~10 => ~122.
// ---------------------------------------------------------------------------
__global__ __launch_bounds__(256) void edge_mfma_kernel(
    const float* __restrict__ rbf, const int* __restrict__ eidx,
    const unsigned short* __restrict__ weffh, const float* __restrict__ beff,
    const float* __restrict__ Pj, const float* __restrict__ Pi,
    float* __restrict__ out, int E)
{
  const int t    = threadIdx.x;
  const int lane = t & 63;
  const int row  = lane & 31;   // chan within tile / A row
  const int half = lane >> 5;   // k-half selector
  const long wid = (long)blockIdx.x * 4 + (t >> 6);
  const long tb  = wid * 32;
  if (tb >= (long)E) return;

  const char* PjB = (const char*)Pj + row * 4;   // chan offset folded in
  const char* PiB = (const char*)Pi + row * 4;

  // ---- packed per-lane indices for the 16 C/D edge rows (hi16=j, lo16=i) --
  int pk[16];
  #pragma unroll
  for (int reg = 0; reg < 16; ++reg) {
    const int erl = (reg & 3) + 8 * (reg >> 2) + 4 * half;
    long eg = tb + erl; if (eg > (long)E - 1) eg = (long)E - 1;
    const int j = eidx[(long)E + eg];   // edge_index[1] -> h_j -> Pj
    const int i = eidx[eg];             // edge_index[0] -> h_i -> Pi
    pk[reg] = (j << 16) | i;
  }

  // ---- A fragments (fp32 -> bf16), NT loads (rbf is read-once) ----
  long er = tb + row; if (er > (long)E - 1) er = (long)E - 1;
  const float* arow = rbf + er * DR + half * 8;
  short8v A[4];
  #pragma unroll
  for (int ks = 0; ks < 4; ++ks) {
    fx4 lo = __builtin_nontemporal_load((const fx4*)&arow[ks * 16]);
    fx4 hi = __builtin_nontemporal_load((const fx4*)&arow[ks * 16 + 4]);
    short8v a;
    a[0] = f2bf(lo.x); a[1] = f2bf(lo.y); a[2] = f2bf(lo.z); a[3] = f2bf(lo.w);
    a[4] = f2bf(hi.x); a[5] = f2bf(hi.y); a[6] = f2bf(hi.z); a[7] = f2bf(hi.w);
    A[ks] = a;
  }

#define LOAD_B(Bv, biasv, ct)                                                  \
  { _Pragma("unroll")                                                          \
    for (int ks = 0; ks < 4; ++ks)                                             \
      Bv[ks] = *(const short8v*)&weffh[((ct) * 32 + row) * DR + ks * 16 + half * 8]; \
    biasv = beff[(ct) * 32 + row]; }

#define ISSUE_G(gjv, giv, ct)                                                  \
  { _Pragma("unroll")                                                          \
    for (int reg = 0; reg < 16; ++reg) {                                       \
      const int jo = (int)(((unsigned)pk[reg] >> 16) << 9);                    \
      const int io = (int)(((unsigned)pk[reg] & 0xFFFFu) << 9);                \
      gjv[reg] = *(const float*)(PjB + (long)jo + (ct) * 128);                 \
      giv[reg] = *(const float*)(PiB + (long)io + (ct) * 128);                 \
    } }

#define MFMA4(accv, Bv, biasv)                                                 \
  { _Pragma("unroll")                                                          \
    for (int i = 0; i < 16; ++i) accv[i] = biasv;                              \
    accv = __builtin_amdgcn_mfma_f32_32x32x16_bf16(A[0], Bv[0], accv, 0, 0, 0);\
    accv = __builtin_amdgcn_mfma_f32_32x32x16_bf16(A[1], Bv[1], accv, 0, 0, 0);\
    accv = __builtin_amdgcn_mfma_f32_32x32x16_bf16(A[2], Bv[2], accv, 0, 0, 0);\
    accv = __builtin_amdgcn_mfma_f32_32x32x16_bf16(A[3], Bv[3], accv, 0, 0, 0); }

#define EPILOG(gjv, giv, accv, ct)                                             \
  { _Pragma("unroll")                                                          \
    for (int reg = 0; reg < 16; ++reg) {                                       \
      const int erl = (reg & 3) + 8 * (reg >> 2) + 4 * half;                   \
      const long ge = tb + erl;                                                \
      const float v = ssp_f(accv[reg] + gjv[reg] + giv[reg]);                  \
      if (ge < (long)E)                                                        \
        __builtin_nontemporal_store(v, &out[ge * D + (ct) * 32 + row]);        \
    } }

  float gjA[16], giA[16], gjB[16], giB[16];
  short8v BA[4], BB[4];
  float biasA, biasB;
  f32x16 acc;

  // prologue: ct0 weights + gathers in flight
  LOAD_B(BA, biasA, 0);
  ISSUE_G(gjA, giA, 0);

  // ct0: issue ct1, compute ct0
  LOAD_B(BB, biasB, 1);
  ISSUE_G(gjB, giB, 1);
  __builtin_amdgcn_sched_barrier(0);
  MFMA4(acc, BA, biasA);
  EPILOG(gjA, giA, acc, 0);

  // ct1: issue ct2, compute ct1
  LOAD_B(BA, biasA, 2);
  ISSUE_G(gjA, giA, 2);
  __builtin_amdgcn_sched_barrier(0);
  MFMA4(acc, BB, biasB);
  EPILOG(gjB, giB, acc, 1);

  // ct2: issue ct3, compute ct2
  LOAD_B(BB, biasB, 3);
  ISSUE_G(gjB, giB, 3);
  __builtin_amdgcn_sched_barrier(0);
  MFMA4(acc, BA, biasA);
  EPILOG(gjA, giA, acc, 2);

  // ct3: compute
  MFMA4(acc, BB, biasB);
  EPILOG(gjB, giB, acc, 3);

#undef LOAD_B
#undef ISSUE_G
#undef MFMA4
#undef EPILOG
}

// ---------------------------------------------------------------------------
// Fallback (ws too small or N >= 2^16): 3 additive passes over out.
// ---------------------------------------------------------------------------
template<int K, int WS, int WOFF, bool GATHER, bool INIT, bool FINAL>
__global__ __launch_bounds__(256) void pass_kernel(
    const float* __restrict__ src, const int* __restrict__ gidx,
    const float* __restrict__ W, const float* __restrict__ beff,
    float* __restrict__ out, int E)
{
  int e = blockIdx.x * 256 + threadIdx.x;
  if (e >= E) return;
  long rowi = GATHER ? (long)gidx[e] : (long)e;

  float4 rv[K / 4];
  const float4* sp = (const float4*)(src + rowi * K);
  #pragma unroll
  for (int c = 0; c < K / 4; ++c) rv[c] = sp[c];

  float* orow = out + (long)e * D;
  for (int ob = 0; ob < D; ob += 4) {
    float acc[4];
    if (INIT) {
      float4 b4 = *(const float4*)&beff[ob];
      acc[0] = b4.x; acc[1] = b4.y; acc[2] = b4.z; acc[3] = b4.w;
    } else {
      float4 p4 = *(const float4*)&orow[ob];
      acc[0] = p4.x; acc[1] = p4.y; acc[2] = p4.z; acc[3] = p4.w;
    }
    #pragma unroll
    for (int k = 0; k < 4; ++k) {
      const float4* wv = (const float4*)&W[(long)(ob + k) * WS + WOFF];
      float a = acc[k];
      #pragma unroll
      for (int c = 0; c < K / 4; ++c) {
        float4 w4 = wv[c]; float4 r4 = rv[c];
        a = fmaf(w4.x, r4.x, a); a = fmaf(w4.y, r4.y, a);
        a = fmaf(w4.z, r4.z, a); a = fmaf(w4.w, r4.w, a);
      }
      acc[k] = a;
    }
    float4 o4;
    o4.x = FINAL ? ssp_f(acc[0]) : acc[0];
    o4.y = FINAL ? ssp_f(acc[1]) : acc[1];
    o4.z = FINAL ? ssp_f(acc[2]) : acc[2];
    o4.w = FINAL ? ssp_f(acc[3]) : acc[3];
    *(float4*)&orow[ob] = o4;
  }
}

// ---------------------------------------------------------------------------
extern "C" void kernel_launch(void* const* d_in, const int* in_sizes, int n_in,
                              void* d_out, int out_size, void* d_ws, size_t ws_size,
                              hipStream_t stream)
{
  const float* vi    = (const float*)d_in[0];
  const float* rbf   = (const float*)d_in[1];
  const float* W_rbf = (const float*)d_in[2];
  const float* b_rbf = (const float*)d_in[3];
  const float* W_cat = (const float*)d_in[4];
  const float* b_cat = (const float*)d_in[5];
  const int*   eidx  = (const int*)d_in[6];

  const int N = in_sizes[0] / D;
  const int E = in_sizes[6] / 2;
  float* out = (float*)d_out;

  float* ws   = (float*)d_ws;
  float* weff = ws;                               // 8192 floats
  float* beff = ws + D * DR;                      // 128 floats (ends 8320)
  unsigned short* weffh = (unsigned short*)(ws + 8448);  // 8192 ushort
  float* Pj   = ws + 8448 + 4096;                 // N*128 floats
  float* Pi   = Pj + (size_t)N * D;
  size_t need = (8448 + 4096 + 2 * (size_t)N * D) * sizeof(float);

  const int use_fast = (ws_size >= need && E >= 1 && N < 65536);
  stage0_kernel<<<32, 256, 0, stream>>>(W_rbf, b_rbf, W_cat, b_cat,
                                        weff, weffh, beff, use_fast);

  if (use_fast) {
    stage1_kernel<<<(N + NB - 1) / NB, 256, 0, stream>>>(vi, W_cat, Pj, Pi, N);
    long waves = ((long)E + 31) / 32;
    int fblocks = (int)((waves + 3) / 4);
    edge_mfma_kernel<<<fblocks, 256, 0, stream>>>(rbf, eidx, weffh, beff,
                                                  Pj, Pi, out, E);
  } else {
    int eblocks = (E + 255) / 256;
    pass_kernel<DR, DR, 0,  false, true,  false><<<eblocks, 256, 0, stream>>>(rbf, nullptr,  weff,  beff, out, E);
    pass_kernel<D, 384, 128, true, false, false><<<eblocks, 256, 0, stream>>>(vi,  eidx + E, W_cat, beff, out, E);
    pass_kernel<D, 384, 256, true, false, true ><<<eblocks, 256, 0, stream>>>(vi,  eidx,     W_cat, beff, out, E);
  }
}